// Round 3
// baseline (570.874 us; speedup 1.0000x reference)
//
#include <hip/hip_runtime.h>
#include <hip/hip_bf16.h>
#include <math.h>

// Problem constants
#define NSEED 4
#define RTOT 409600          // N * NS
#define EE 128
#define KP1 96               // 72 -> 96 (pad)
#define KP2 128
#define KP3 160              // 159 -> 160 (pad)
#define PH 136               // shorts; per-wave act buffer stride (68 dw, 2-way banks)

typedef short bf16x8 __attribute__((ext_vector_type(8)));
typedef float f32x4 __attribute__((ext_vector_type(4)));
typedef int   i32x4 __attribute__((ext_vector_type(4)));

static __device__ __forceinline__ short f2bf(float x) {
    __hip_bfloat16 h = __float2bfloat16(x);  // RNE
    return __builtin_bit_cast(short, h);
}

static __device__ __forceinline__ int pack2(float a, float b) {
    return (int)(unsigned short)f2bf(a) | ((int)(unsigned short)f2bf(b) << 16);
}

static __device__ __forceinline__ float gelu_fast(float x) {
    // x * sigmoid(1.702 x); |err| vs exact-erf gelu <= ~5e-3 for |x|<~1.5,
    // out-level impact ~2e-4 after two 0.02-std weight layers.
    return x / (1.0f + __expf(-1.702f * x));
}

// ---- prep: transposed bf16 weights + fourier table into d_ws ----
// ws (shorts): W1T[128][96] @0 | W2T[128][128] @12288 | WpT[128][160] @28672 | disp[64][32] @49152
__global__ void prep_tables(const float* __restrict__ W1, const float* __restrict__ W2,
                            const float* __restrict__ Wp, short* __restrict__ ws) {
    const int i = blockIdx.x * 256 + threadIdx.x;
    if (i < 12288) {
        const int e = i / KP1, k = i - e * KP1;
        ws[i] = (k < 72) ? f2bf(W1[k * EE + e]) : (short)0;
    } else if (i < 28672) {
        const int j = i - 12288; const int e = j >> 7, k = j & 127;
        ws[i] = f2bf(W2[k * EE + e]);
    } else if (i < 49152) {
        const int j = i - 28672; const int e = j / KP3, k = j - e * KP3;
        ws[i] = (k < 159) ? f2bf(Wp[k * EE + e]) : (short)0;
    } else if (i < 51200) {
        const int j = i - 49152; const int sd = j >> 5, jj = j & 31;
        const float coord = (float)sd * (float)(3.14 / 64.0);
        float v;
        if (jj < 15) v = sinf(coord * (float)(1 << jj));
        else if (jj < 30) v = cosf(coord * (float)(1 << (jj - 15)));
        else if (jj == 30) v = coord;
        else v = 0.0f;  // k=159 pad
        ws[i] = f2bf(v);
    }
}

// Barrier-free main kernel: one wave owns 16 rows (4 pixels x 4 seeds).
__global__ __launch_bounds__(256, 4)
void Propagation_85315230368231_kernel(const float* __restrict__ cost_volume,
                                       const int* __restrict__ label_seed,
                                       const short* __restrict__ ws,
                                       const float* __restrict__ b1,
                                       const float* __restrict__ b2,
                                       float* __restrict__ out) {
    __shared__ short sH[4][16 * PH];  // 4 x 4352 B = 17408 B / block

    const short* W1T = ws;
    const short* W2T = ws + 12288;
    const short* WpT = ws + 28672;
    const short* DSP = ws + 49152;

    const int tid = threadIdx.x;
    const int wave = tid >> 6;
    const int lane = tid & 63;
    const int ln = lane & 15;   // activation row within wave (n of MFMA)
    const int qd = lane >> 4;   // k-quad
    short* sHw = sH[wave];

    const int gw = blockIdx.x * 4 + wave;   // global wave id
    const int row0 = gw * 16;
    const int row = row0 + ln;              // this lane's activation row
    const int n = row >> 2;                 // pixel (NSEED=4)

    const int sd = label_seed[row];
    if (qd == 0) {
        __builtin_nontemporal_store((float)sd, out + (size_t)RTOT * EE + row);
    }

    // disparity-encoding B-frag (stage-3 k-step 4) straight from table
    const bf16x8 db = *(const bf16x8*)(DSP + sd * 32 + 8 * qd);

    // ---- gather cost directly into stage-1 B-frags ----
    const float* cvn = cost_volume + (size_t)n * 512;
    i32x4 cb[3];
#pragma unroll
    for (int ks = 0; ks < 3; ++ks) {
#pragma unroll
        for (int d = 0; d < 4; ++d) {
            int pk = 0;
#pragma unroll
            for (int e = 0; e < 2; ++e) {
                const int k = ks * 32 + qd * 8 + 2 * d + e;
                if (k < 72) {
                    const int g = k / 9;
                    int dd = sd + (k - g * 9) - 4;
                    dd = dd < 0 ? 0 : (dd > 63 ? 63 : dd);
                    const float x = cvn[(g << 6) + dd];
                    pk |= ((int)(unsigned short)f2bf(x)) << (16 * e);
                }
            }
            cb[ks][d] = pk;
        }
    }

    // ---- stage 1: h = gelu(cost @ W1 + b1), bias folded into acc init ----
    f32x4 acc[8];
#pragma unroll
    for (int mt = 0; mt < 8; ++mt) acc[mt] = *(const f32x4*)(b1 + mt * 16 + 4 * qd);
#pragma unroll
    for (int ks = 0; ks < 3; ++ks) {
        const bf16x8 bf = __builtin_bit_cast(bf16x8, cb[ks]);
#pragma unroll
        for (int mt = 0; mt < 8; ++mt) {
            const bf16x8 a = *(const bf16x8*)(W1T + (mt * 16 + ln) * KP1 + ks * 32 + qd * 8);
            acc[mt] = __builtin_amdgcn_mfma_f32_16x16x32_bf16(a, bf, acc[mt], 0, 0, 0);
        }
    }
    // epilogue: gelu + pack -> per-wave LDS [row][e]
#pragma unroll
    for (int mt = 0; mt < 8; ++mt) {
        int2 w;
        w.x = pack2(gelu_fast(acc[mt][0]), gelu_fast(acc[mt][1]));
        w.y = pack2(gelu_fast(acc[mt][2]), gelu_fast(acc[mt][3]));
        *(int2*)(sHw + ln * PH + mt * 16 + 4 * qd) = w;
    }
    // cross-lane LDS handoff within the wave: lockstep + drain
    __asm__ volatile("s_waitcnt lgkmcnt(0)" ::: "memory");

    // ---- stage 2: F = h @ W2 + b2 ----
    f32x4 acc2[8];
#pragma unroll
    for (int mt = 0; mt < 8; ++mt) acc2[mt] = *(const f32x4*)(b2 + mt * 16 + 4 * qd);
#pragma unroll
    for (int ks = 0; ks < 4; ++ks) {
        const bf16x8 hb = *(const bf16x8*)(sHw + ln * PH + ks * 32 + qd * 8);
#pragma unroll
        for (int mt = 0; mt < 8; ++mt) {
            const bf16x8 a = *(const bf16x8*)(W2T + (mt * 16 + ln) * KP2 + ks * 32 + qd * 8);
            acc2[mt] = __builtin_amdgcn_mfma_f32_16x16x32_bf16(a, hb, acc2[mt], 0, 0, 0);
        }
    }
    // pack F over the h buffer (data-dep on all reads via MFMA -> safe to overwrite)
#pragma unroll
    for (int mt = 0; mt < 8; ++mt) {
        int2 w;
        w.x = pack2(acc2[mt][0], acc2[mt][1]);
        w.y = pack2(acc2[mt][2], acc2[mt][3]);
        *(int2*)(sHw + ln * PH + mt * 16 + 4 * qd) = w;
    }
    __asm__ volatile("s_waitcnt lgkmcnt(0)" ::: "memory");

    // ---- stage 3: out = [F | disp] @ Wp ----
    f32x4 acc3[8];
#pragma unroll
    for (int mt = 0; mt < 8; ++mt) acc3[mt] = (f32x4)0.0f;
#pragma unroll
    for (int ks = 0; ks < 4; ++ks) {
        const bf16x8 fb = *(const bf16x8*)(sHw + ln * PH + ks * 32 + qd * 8);
#pragma unroll
        for (int mt = 0; mt < 8; ++mt) {
            const bf16x8 a = *(const bf16x8*)(WpT + (mt * 16 + ln) * KP3 + ks * 32 + qd * 8);
            acc3[mt] = __builtin_amdgcn_mfma_f32_16x16x32_bf16(a, fb, acc3[mt], 0, 0, 0);
        }
    }
#pragma unroll
    for (int mt = 0; mt < 8; ++mt) {
        const bf16x8 a = *(const bf16x8*)(WpT + (mt * 16 + ln) * KP3 + 128 + qd * 8);
        acc3[mt] = __builtin_amdgcn_mfma_f32_16x16x32_bf16(a, db, acc3[mt], 0, 0, 0);
    }

    // ---- store out[row][e] : lane holds e = 16mt + 4qd + r for its row ----
    float* orow = out + (size_t)row * EE;
#pragma unroll
    for (int mt = 0; mt < 8; ++mt) {
        __builtin_nontemporal_store(acc3[mt], (f32x4*)(orow + mt * 16 + 4 * qd));
    }
}

extern "C" void kernel_launch(void* const* d_in, const int* in_sizes, int n_in,
                              void* d_out, int out_size, void* d_ws, size_t ws_size,
                              hipStream_t stream) {
    const float* cost_volume = (const float*)d_in[0];
    const int* label_seed = (const int*)d_in[1];
    // d_in[2] = context: unused (layers=[], norm=None)
    const float* W1 = (const float*)d_in[3];
    const float* b1 = (const float*)d_in[4];
    const float* W2 = (const float*)d_in[5];
    const float* b2 = (const float*)d_in[6];
    const float* Wp = (const float*)d_in[7];
    float* out = (float*)d_out;
    short* ws = (short*)d_ws;  // needs 51200 shorts = 100 KB

    prep_tables<<<200, 256, 0, stream>>>(W1, W2, Wp, ws);
    Propagation_85315230368231_kernel<<<RTOT / 64, 256, 0, stream>>>(
        cost_volume, label_seed, ws, b1, b2, out);
}